// Round 5
// baseline (134.045 us; speedup 1.0000x reference)
//
#include <hip/hip_runtime.h>
#include <math.h>

#define ROW_C 512
#define NBIN 2048
#define NPACK (NBIN / 2)   // two 16-bit counters per int -> 1024 ints = 4KB/wave
#define RPW 4              // rows per wave

// FOUR rows per wave (8 elems/lane each), one 4KB per-wave histogram reused
// serially, software-pipelined per row i:
//   [load x(i+1)] -> FRONT(i) (last LDS reads) -> [ZERO+HIST(i+1), early DS]
//   -> BACK(i) (pure VALU/DPP, hides next row's atomics + the prefetch's HBM)
// Only xc[8]+xn[8] live across phases -> ~50 VGPR; __launch_bounds__(256,8)
// pins 8 blocks/CU = 32 waves/CU. Grid = 2048 blocks = exactly one residency
// generation on 256 CUs.
// Selection per row (verified rounds 1-4):
//  1. value-uniform 2048-bin histogram over octave [8,16) (clamp +-3.90625,
//     +12.0 -> bin width 1/256; bits [22:12] monotone). Packed u16x2 LDS
//     counters, XOR-swizzled so int4 reads/writes are bank-conflict-free.
//  2. per-lane packed totals + DPP 64-lane inclusive scan (0 DS); ballots ->
//     owner lanes (SGPR); 16-lanes-per-rank crossing scan (one word/lane,
//     4-step DPP row scan, ballot). NO ds_bpermute anywhere: owner prefix and
//     crossing word are fetched via v_readlane at SGPR lane indices, and all
//     per-rank finalize math (bsel, R, all-in, threshold) is wave-uniform.
//  3. nested-set float thresholds t1>=t2>=t3>=t4 (all-in -> exact bin lower
//     edge, bin<=24 -> -inf; partial -> exact tail wave-max via DPP+readlane);
//     membership = x>=t_r; epilogue = 4-deep cndmask chain into wz prefix sums.
//  4. rare exact-duplicate index-tiebreak -> wave-uniform fallback (matches
//     jax.lax.top_k lowest-index rule).
// Softmax shift term omitted (shift-invariant). No __syncthreads (wave-private
// LDS, in-order DS pipe). Assumes finite inputs.

static __device__ __forceinline__ unsigned scan64_add(unsigned v) {
    int x = (int)v;
    x += __builtin_amdgcn_update_dpp(0, x, 0x111, 0xF, 0xF, false); // row_shr:1
    x += __builtin_amdgcn_update_dpp(0, x, 0x112, 0xF, 0xF, false); // row_shr:2
    x += __builtin_amdgcn_update_dpp(0, x, 0x114, 0xF, 0xE, false); // row_shr:4
    x += __builtin_amdgcn_update_dpp(0, x, 0x118, 0xF, 0xC, false); // row_shr:8
    x += __builtin_amdgcn_update_dpp(0, x, 0x142, 0xA, 0xF, false); // row_bcast:15
    x += __builtin_amdgcn_update_dpp(0, x, 0x143, 0xC, 0xF, false); // row_bcast:31
    return (unsigned)x;
}

static __device__ __forceinline__ unsigned scan16_add(unsigned v) {
    int x = (int)v;
    x += __builtin_amdgcn_update_dpp(0, x, 0x111, 0xF, 0xF, false);
    x += __builtin_amdgcn_update_dpp(0, x, 0x112, 0xF, 0xF, false);
    x += __builtin_amdgcn_update_dpp(0, x, 0x114, 0xF, 0xE, false);
    x += __builtin_amdgcn_update_dpp(0, x, 0x118, 0xF, 0xC, false);
    return (unsigned)x;
}

static __device__ __forceinline__ float wave_fadd_red(float v) {
    float t;
    t = __int_as_float(__builtin_amdgcn_update_dpp(0, __float_as_int(v), 0x111, 0xF, 0xF, false)); v += t;
    t = __int_as_float(__builtin_amdgcn_update_dpp(0, __float_as_int(v), 0x112, 0xF, 0xF, false)); v += t;
    t = __int_as_float(__builtin_amdgcn_update_dpp(0, __float_as_int(v), 0x114, 0xF, 0xE, false)); v += t;
    t = __int_as_float(__builtin_amdgcn_update_dpp(0, __float_as_int(v), 0x118, 0xF, 0xC, false)); v += t;
    t = __int_as_float(__builtin_amdgcn_update_dpp(0, __float_as_int(v), 0x142, 0xA, 0xF, false)); v += t;
    t = __int_as_float(__builtin_amdgcn_update_dpp(0, __float_as_int(v), 0x143, 0xC, 0xF, false)); v += t;
    return __int_as_float(__builtin_amdgcn_readlane(__float_as_int(v), 63));
}

static __device__ __forceinline__ float wave_fmax_red(float v) {
    const int NI = (int)0xFF800000;
    float t;
    t = __int_as_float(__builtin_amdgcn_update_dpp(NI, __float_as_int(v), 0x111, 0xF, 0xF, false)); v = fmaxf(v, t);
    t = __int_as_float(__builtin_amdgcn_update_dpp(NI, __float_as_int(v), 0x112, 0xF, 0xF, false)); v = fmaxf(v, t);
    t = __int_as_float(__builtin_amdgcn_update_dpp(NI, __float_as_int(v), 0x114, 0xF, 0xE, false)); v = fmaxf(v, t);
    t = __int_as_float(__builtin_amdgcn_update_dpp(NI, __float_as_int(v), 0x118, 0xF, 0xC, false)); v = fmaxf(v, t);
    t = __int_as_float(__builtin_amdgcn_update_dpp(NI, __float_as_int(v), 0x142, 0xA, 0xF, false)); v = fmaxf(v, t);
    t = __int_as_float(__builtin_amdgcn_update_dpp(NI, __float_as_int(v), 0x143, 0xC, 0xF, false)); v = fmaxf(v, t);
    return __int_as_float(__builtin_amdgcn_readlane(__float_as_int(v), 63));
}

__global__ __launch_bounds__(256, 8) void topk_ms_kernel(
    const float* __restrict__ attn,
    const float* __restrict__ w1p, const float* __restrict__ w2p,
    const float* __restrict__ w3p, const float* __restrict__ w4p,
    float* __restrict__ out)
{
    __shared__ __align__(16) unsigned hist_all[4][NPACK];

    const int lane = threadIdx.x & 63;
    const int wv   = threadIdx.x >> 6;
    unsigned* h = hist_all[wv];
    int4* hv = (int4*)h;

    const float W1 = w1p[0], W2 = w2p[0], W3 = w3p[0], W4 = w4p[0];
    const float NINF = -__builtin_inff();

    const long long gid   = (long long)blockIdx.x * 4 + wv;   // wave id
    const long long base0 = gid * (RPW * ROW_C) + lane * 8;

    auto BINF = [](float v) -> int {
        const float y = __builtin_amdgcn_fmed3f(v, -3.90625f, 3.90625f) + 12.0f;
        return (int)((__float_as_uint(y) >> 12) & 0x7FFu);   // monotone, width 1/256
    };

    auto ZERO = [&]() {
        const int4 z = make_int4(0, 0, 0, 0);
        hv[lane] = z; hv[lane + 64] = z; hv[lane + 128] = z; hv[lane + 192] = z;
    };

    auto HIST = [&](const float* x) {
        #pragma unroll
        for (int s = 0; s < 8; ++s) {
            const int b  = BINF(x[s]);
            const int j  = b >> 1;
            const int ph = j ^ ((j >> 3) & 0x1C);   // XOR swizzle bits[7:5]->[4:2]
            atomicAdd(&h[ph], (b & 1) ? 0x10000u : 1u);
        }
    };

    // front-end: histogram -> per-rank {threshold, bin, R, all-in}; no bpermute
    auto FRONT = [&](float* tthr, int* b_, int* R_, int* al_) {
        unsigned ps = 0;
        #pragma unroll
        for (int k = 0; k < 4; ++k) {
            const int b  = 4 * lane + k;
            const int pb = b ^ ((b >> 3) & 7);
            const int4 v = hv[pb];
            ps += (unsigned)v.x + (unsigned)v.y + (unsigned)v.z + (unsigned)v.w;
        }
        const unsigned tot  = (ps & 0xFFFFu) + (ps >> 16);
        const unsigned incl = scan64_add(tot);
        const unsigned excl = incl - tot;

        const unsigned long long Ba = __ballot(incl >= 257u);
        const unsigned long long Bb = __ballot(incl >= 172u);
        const unsigned long long Bc = __ballot(incl >= 129u);
        const unsigned long long Bd = __ballot(incl >= 104u);
        const int l0 = __ffsll(Ba) - 1, l1 = __ffsll(Bb) - 1,
                  l2 = __ffsll(Bc) - 1, l3 = __ffsll(Bd) - 1;

        // owner prefix per rank: readlane at SGPR lane index (no bpermute)
        const unsigned e0 = (unsigned)__builtin_amdgcn_readlane((int)excl, l0);
        const unsigned e1 = (unsigned)__builtin_amdgcn_readlane((int)excl, l1);
        const unsigned e2 = (unsigned)__builtin_amdgcn_readlane((int)excl, l2);
        const unsigned e3 = (unsigned)__builtin_amdgcn_readlane((int)excl, l3);

        const int r = lane >> 4;                   // rank group of this lane
        const int lsel = (r == 0) ? l0 : (r == 1) ? l1 : (r == 2) ? l2 : l3;
        const int Tr   = (r == 0) ? 257 : (r == 1) ? 172 : (r == 2) ? 129 : 104;
        const unsigned exl = (r == 0) ? e0 : (r == 1) ? e1 : (r == 2) ? e2 : e3;

        const int jw = (lsel << 4) + (lane & 15);  // logical word index
        const int pw = jw ^ ((jw >> 3) & 0x1C);    // same swizzle as atomics
        const unsigned w0 = h[pw];
        const unsigned q  = w0 + (w0 << 16);       // packed (even, even+odd)
        const unsigned wt = q >> 16;
        const unsigned sc = scan16_add(wt);
        const unsigned ebase = exl + (sc - wt);    // global prefix before word
        const int      phi   = (int)(ebase + wt);
        const unsigned long long CB = __ballot(phi >= Tr);

        const int Ls[4] = {l0, l1, l2, l3};
        const int Ts[4] = {257, 172, 129, 104};
        const int Ks[4] = {256, 341, 384, 409};
        #pragma unroll
        for (int rr = 0; rr < 4; ++rr) {
            const unsigned cb = (unsigned)(CB >> (rr << 4)) & 0xFFFFu;
            const int js = __ffs(cb) - 1;                       // SALU, nonzero
            const int li = (rr << 4) + js;
            const unsigned qw  = (unsigned)__builtin_amdgcn_readlane((int)q, li);
            const unsigned ebw = (unsigned)__builtin_amdgcn_readlane((int)ebase, li);
            const int  plo  = (int)(ebw + (qw & 0xFFFFu));      // pref at even bin
            const int  phw  = (int)(ebw + (qw >> 16));          // pref at odd bin
            const bool ev   = (plo >= Ts[rr]);
            const int  bsel = (((Ls[rr] << 4) + js) << 1) + (ev ? 0 : 1);
            const int  locp = ev ? plo : phw;
            const int  prvp = ev ? (int)ebw : plo;
            b_[rr]  = bsel;
            R_[rr]  = Ks[rr] - 512 + locp;                      // rank in bin >=1
            al_[rr] = (prvp == Ts[rr] - 1) ? 1 : 0;             // whole bin in
            const float t = __uint_as_float((unsigned)(bsel + 0x41000) << 12) - 12.0f;
            tthr[rr] = (bsel <= 24) ? NINF : t;                 // clamp bin: all
        }
    };

    // back-end: exact tail + softmax + weighted epilogue + store (LDS-free)
    auto BACK = [&](const float* x, float* tthr, const int* b_, const int* R_,
                    const int* al_, long long obase) {
        int needv[4] = {0,0,0,0}, cntv[4] = {0,0,0,0};
        bool anytb = false;
        const bool needbins = !(al_[0] && al_[1] && al_[2] && al_[3]);
        int bn[8];
        if (needbins) {
            #pragma unroll
            for (int s = 0; s < 8; ++s) bn[s] = BINF(x[s]);
        }
        #pragma unroll
        for (int rr = 0; rr < 4; ++rr) {
            if (!al_[rr]) {                        // wave-uniform (SGPR) branch
                float cm[8];
                #pragma unroll
                for (int s = 0; s < 8; ++s)
                    cm[s] = (bn[s] == b_[rr]) ? x[s] : NINF;
                int R = R_[rr];
                float t; int c;
                while (true) {
                    float mk = cm[0];
                    #pragma unroll
                    for (int s = 1; s < 8; ++s) mk = fmaxf(mk, cm[s]);
                    t = wave_fmax_red(mk);
                    c = 0;
                    #pragma unroll
                    for (int s = 0; s < 8; ++s)
                        c += (int)__popcll(__ballot(cm[s] == t));
                    if (c >= R) break;
                    R -= c;
                    #pragma unroll
                    for (int s = 0; s < 8; ++s)
                        cm[s] = (cm[s] == t) ? NINF : cm[s];
                }
                tthr[rr] = t; needv[rr] = R; cntv[rr] = c;
                anytb = anytb || (c != R);
            }
        }

        float eo[8];
        #pragma unroll
        for (int s = 0; s < 8; ++s) eo[s] = __expf(x[s]);

        float res[8];
        if (!anytb) {
            // fast path: 4 nested float thresholds t1>=t2>=t3>=t4
            const float t1 = tthr[0], t2 = tthr[1], t3 = tthr[2], t4 = tthr[3];
            float z0 = 0.f, z1 = 0.f, z2 = 0.f, z3 = 0.f;
            #pragma unroll
            for (int s = 0; s < 8; ++s) {
                z0 += (x[s] >= t1) ? eo[s] : 0.f;
                z1 += (x[s] >= t2) ? eo[s] : 0.f;
                z2 += (x[s] >= t3) ? eo[s] : 0.f;
                z3 += (x[s] >= t4) ? eo[s] : 0.f;
            }
            const float Z0 = wave_fadd_red(z0);
            const float Z1 = wave_fadd_red(z1);
            const float Z2 = wave_fadd_red(z2);
            const float Z3 = wave_fadd_red(z3);
            const float wz0 = W1 * __builtin_amdgcn_rcpf(Z0);
            const float wz1 = W2 * __builtin_amdgcn_rcpf(Z1);
            const float wz2 = W3 * __builtin_amdgcn_rcpf(Z2);
            const float wz3 = W4 * __builtin_amdgcn_rcpf(Z3);
            const float u4 = wz3, u3 = u4 + wz2, u2 = u3 + wz1, u1 = u2 + wz0;
            #pragma unroll
            for (int s = 0; s < 8; ++s) {
                float c = (x[s] >= t1) ? u1 : u2;
                c = (x[s] >= t2) ? c : u3;
                c = (x[s] >= t3) ? c : u4;
                c = (x[s] >= t4) ? c : 0.f;
                res[s] = eo[s] * c;
            }
        } else {
            // slow path (exact-duplicate tiebreak): general fl bitmask
            int fl[8] = {0, 0, 0, 0, 0, 0, 0, 0};
            #pragma unroll
            for (int rr = 0; rr < 4; ++rr) {
                const float t = tthr[rr];
                if (al_[rr] || needv[rr] == cntv[rr]) {
                    #pragma unroll
                    for (int s = 0; s < 8; ++s)
                        fl[s] |= ((int)(x[s] >= t)) << rr;
                } else {                            // admit lowest original idx
                    const unsigned long long ltm = (1ull << lane) - 1ull;
                    int basec = 0;
                    #pragma unroll
                    for (int s = 0; s < 8; ++s)
                        basec += (int)__popcll(__ballot(x[s] == t) & ltm);
                    int own = 0;
                    #pragma unroll
                    for (int s = 0; s < 8; ++s) {
                        const bool eq = (x[s] == t);
                        if (x[s] > t || (eq && (basec + own) < needv[rr]))
                            fl[s] |= (1 << rr);
                        own += eq ? 1 : 0;
                    }
                }
            }
            float z0 = 0.f, z1 = 0.f, z2 = 0.f, z3 = 0.f;
            #pragma unroll
            for (int s = 0; s < 8; ++s) {
                z0 += (fl[s] & 1) ? eo[s] : 0.f;
                z1 += (fl[s] & 2) ? eo[s] : 0.f;
                z2 += (fl[s] & 4) ? eo[s] : 0.f;
                z3 += (fl[s] & 8) ? eo[s] : 0.f;
            }
            const float Z0 = wave_fadd_red(z0);
            const float Z1 = wave_fadd_red(z1);
            const float Z2 = wave_fadd_red(z2);
            const float Z3 = wave_fadd_red(z3);
            const float wz0 = W1 * __builtin_amdgcn_rcpf(Z0);
            const float wz1 = W2 * __builtin_amdgcn_rcpf(Z1);
            const float wz2 = W3 * __builtin_amdgcn_rcpf(Z2);
            const float wz3 = W4 * __builtin_amdgcn_rcpf(Z3);
            #pragma unroll
            for (int s = 0; s < 8; ++s) {
                float c = 0.f;
                c += (fl[s] & 1) ? wz0 : 0.f;
                c += (fl[s] & 2) ? wz1 : 0.f;
                c += (fl[s] & 4) ? wz2 : 0.f;
                c += (fl[s] & 8) ? wz3 : 0.f;
                res[s] = eo[s] * c;
            }
        }

        *reinterpret_cast<float4*>(out + obase)     = make_float4(res[0], res[1], res[2], res[3]);
        *reinterpret_cast<float4*>(out + obase + 4) = make_float4(res[4], res[5], res[6], res[7]);
    };

    // ---- pipelined 4-row schedule ----
    float xc[8], xn[8];
    {
        const float4 A = *reinterpret_cast<const float4*>(attn + base0);
        const float4 B = *reinterpret_cast<const float4*>(attn + base0 + 4);
        xc[0]=A.x; xc[1]=A.y; xc[2]=A.z; xc[3]=A.w;
        xc[4]=B.x; xc[5]=B.y; xc[6]=B.z; xc[7]=B.w;
    }
    ZERO();
    HIST(xc);

    #pragma unroll
    for (int i = 0; i < RPW; ++i) {
        const long long basei = base0 + (long long)i * ROW_C;
        if (i + 1 < RPW) {                        // prefetch next row (HBM
            const long long basen = basei + ROW_C;//  latency hides under FRONT+BACK)
            const float4 A = *reinterpret_cast<const float4*>(attn + basen);
            const float4 B = *reinterpret_cast<const float4*>(attn + basen + 4);
            xn[0]=A.x; xn[1]=A.y; xn[2]=A.z; xn[3]=A.w;
            xn[4]=B.x; xn[5]=B.y; xn[6]=B.z; xn[7]=B.w;
        }
        float tthr[4]; int b_[4], R_[4], al_[4];
        FRONT(tthr, b_, R_, al_);                 // last LDS reads of row i
        if (i + 1 < RPW) { ZERO(); HIST(xn); }    // early DS for row i+1
        BACK(xc, tthr, b_, R_, al_, basei);       // VALU-heavy: hides the above
        if (i + 1 < RPW) {
            #pragma unroll
            for (int s = 0; s < 8; ++s) xc[s] = xn[s];
        }
    }
}

extern "C" void kernel_launch(void* const* d_in, const int* in_sizes, int n_in,
                              void* d_out, int out_size, void* d_ws, size_t ws_size,
                              hipStream_t stream) {
    const float* attn = (const float*)d_in[0];
    const float* w1   = (const float*)d_in[1];
    const float* w2   = (const float*)d_in[2];
    const float* w3   = (const float*)d_in[3];
    const float* w4   = (const float*)d_in[4];
    float* out = (float*)d_out;

    int rows   = in_sizes[0] / ROW_C;         // 8*8*512 = 32768
    int waves  = rows / RPW;                  // 4 rows per wave -> 8192
    int blocks = (waves + 3) / 4;             // 4 waves/block -> 2048 blocks
    topk_ms_kernel<<<blocks, 256, 0, stream>>>(attn, w1, w2, w3, w4, out);
}

// Round 6
// 125.362 us; speedup vs baseline: 1.0693x; 1.0693x over previous
//
#include <hip/hip_runtime.h>
#include <math.h>

#define ROW_C 512
#define NBIN 1024
#define NPACK (NBIN / 2)   // two 16-bit counters per int -> 512 ints = 2KB/wave

// One wave per row, 8 elements/lane (round-3 structure, best verified).
// Selection of the K-th largest for K in {256,341,384,409}:
//  1. value-uniform 1024-bin histogram, bin width 1/256 (same as the verified
//     2048-bin version; range clamp [-3.5, 0.484375], +11.5 -> y in [8,12),
//     bits [22:12] monotone). Thresholds for these K lie in ~[-1.2,0.3], deep
//     inside the range; clamp bins are handled exactly by the tail loop.
//     Packed u16x2 LDS counters, XOR-swizzled (j ^ ((j>>3)&0x38), preserves
//     int4 blocks) so vector reads/writes are bank-conflict-spread.
//  2. per-lane packed totals (2 int4) + DPP 64-lane inclusive scan (0 DS);
//     ballots -> owner lanes (SGPR). Crossing scan: 16-lane groups, one word
//     per lane (owner has 8 words; lanes 8-15 padded, masked by ffs), 4-step
//     DPP row scan + ballot. NO ds_bpermute anywhere: owner prefix and
//     crossing word fetched via v_readlane at SGPR lane indices; per-rank
//     finalize math (bsel, R, all-in, threshold) is wave-uniform.
//  3. nested-set float thresholds t1>=t2>=t3>=t4 (all-in -> exact bin lower
//     edge, bin 0 -> -inf; partial -> exact tail wave-max via DPP+readlane);
//     membership = x>=t_r; epilogue = 4-deep cndmask chain into wz prefix sums.
//  4. rare exact-duplicate index-tiebreak -> wave-uniform fallback (matches
//     jax.lax.top_k lowest-index rule).
// No cross-row ILP (rounds 4/5 showed it is neutral-to-negative: VGPR/spill
// cliffs). No __syncthreads (wave-private LDS, in-order DS pipe). Assumes
// finite inputs.

static __device__ __forceinline__ unsigned scan64_add(unsigned v) {
    int x = (int)v;
    x += __builtin_amdgcn_update_dpp(0, x, 0x111, 0xF, 0xF, false); // row_shr:1
    x += __builtin_amdgcn_update_dpp(0, x, 0x112, 0xF, 0xF, false); // row_shr:2
    x += __builtin_amdgcn_update_dpp(0, x, 0x114, 0xF, 0xE, false); // row_shr:4
    x += __builtin_amdgcn_update_dpp(0, x, 0x118, 0xF, 0xC, false); // row_shr:8
    x += __builtin_amdgcn_update_dpp(0, x, 0x142, 0xA, 0xF, false); // row_bcast:15
    x += __builtin_amdgcn_update_dpp(0, x, 0x143, 0xC, 0xF, false); // row_bcast:31
    return (unsigned)x;
}

static __device__ __forceinline__ unsigned scan16_add(unsigned v) {
    int x = (int)v;
    x += __builtin_amdgcn_update_dpp(0, x, 0x111, 0xF, 0xF, false);
    x += __builtin_amdgcn_update_dpp(0, x, 0x112, 0xF, 0xF, false);
    x += __builtin_amdgcn_update_dpp(0, x, 0x114, 0xF, 0xE, false);
    x += __builtin_amdgcn_update_dpp(0, x, 0x118, 0xF, 0xC, false);
    return (unsigned)x;
}

static __device__ __forceinline__ float wave_fadd_red(float v) {
    float t;
    t = __int_as_float(__builtin_amdgcn_update_dpp(0, __float_as_int(v), 0x111, 0xF, 0xF, false)); v += t;
    t = __int_as_float(__builtin_amdgcn_update_dpp(0, __float_as_int(v), 0x112, 0xF, 0xF, false)); v += t;
    t = __int_as_float(__builtin_amdgcn_update_dpp(0, __float_as_int(v), 0x114, 0xF, 0xE, false)); v += t;
    t = __int_as_float(__builtin_amdgcn_update_dpp(0, __float_as_int(v), 0x118, 0xF, 0xC, false)); v += t;
    t = __int_as_float(__builtin_amdgcn_update_dpp(0, __float_as_int(v), 0x142, 0xA, 0xF, false)); v += t;
    t = __int_as_float(__builtin_amdgcn_update_dpp(0, __float_as_int(v), 0x143, 0xC, 0xF, false)); v += t;
    return __int_as_float(__builtin_amdgcn_readlane(__float_as_int(v), 63));
}

static __device__ __forceinline__ float wave_fmax_red(float v) {
    const int NI = (int)0xFF800000;
    float t;
    t = __int_as_float(__builtin_amdgcn_update_dpp(NI, __float_as_int(v), 0x111, 0xF, 0xF, false)); v = fmaxf(v, t);
    t = __int_as_float(__builtin_amdgcn_update_dpp(NI, __float_as_int(v), 0x112, 0xF, 0xF, false)); v = fmaxf(v, t);
    t = __int_as_float(__builtin_amdgcn_update_dpp(NI, __float_as_int(v), 0x114, 0xF, 0xE, false)); v = fmaxf(v, t);
    t = __int_as_float(__builtin_amdgcn_update_dpp(NI, __float_as_int(v), 0x118, 0xF, 0xC, false)); v = fmaxf(v, t);
    t = __int_as_float(__builtin_amdgcn_update_dpp(NI, __float_as_int(v), 0x142, 0xA, 0xF, false)); v = fmaxf(v, t);
    t = __int_as_float(__builtin_amdgcn_update_dpp(NI, __float_as_int(v), 0x143, 0xC, 0xF, false)); v = fmaxf(v, t);
    return __int_as_float(__builtin_amdgcn_readlane(__float_as_int(v), 63));
}

__global__ __launch_bounds__(256) void topk_ms_kernel(
    const float* __restrict__ attn,
    const float* __restrict__ w1p, const float* __restrict__ w2p,
    const float* __restrict__ w3p, const float* __restrict__ w4p,
    float* __restrict__ out)
{
    __shared__ __align__(16) unsigned hist_all[4][NPACK];

    const int lane = threadIdx.x & 63;
    const int wv   = threadIdx.x >> 6;
    unsigned* h = hist_all[wv];
    int4* hv = (int4*)h;

    const long long row  = (long long)blockIdx.x * 4 + wv;
    const long long base = row * ROW_C + lane * 8;

    const float4 A = *reinterpret_cast<const float4*>(attn + base);
    const float4 B = *reinterpret_cast<const float4*>(attn + base + 4);
    float x[8] = {A.x, A.y, A.z, A.w, B.x, B.y, B.z, B.w};

    int bin[8];
    #pragma unroll
    for (int s = 0; s < 8; ++s) {
        // clamp [-3.5, 0.484375] (both exact), +11.5 -> y in [8.0, 11.984375]
        const float y = __builtin_amdgcn_fmed3f(x[s], -3.5f, 0.484375f) + 11.5f;
        bin[s] = (int)((__float_as_uint(y) >> 12) & 0x7FFu);   // 0..1020, width 1/256
    }

    // ---- zero histogram (128 int4) ----
    {
        const int4 z = make_int4(0, 0, 0, 0);
        hv[lane] = z; hv[lane + 64] = z;
    }

    // ---- histogram: packed atomic adds, swizzled (j ^ ((j>>3)&0x38)) ----
    #pragma unroll
    for (int s = 0; s < 8; ++s) {
        const int j  = bin[s] >> 1;
        const int ph = j ^ ((j >> 3) & 0x38);
        atomicAdd(&h[ph], (bin[s] & 1) ? 0x10000u : 1u);
    }

    // ---- per-lane raw totals of own 16 bins (words 8l..8l+7, 2 int4) ----
    unsigned ps = 0;
    unsigned wreg[8];
    #pragma unroll
    for (int k = 0; k < 2; ++k) {
        const int Bb = 2 * lane + k;
        const int pb = Bb ^ ((Bb >> 3) & 0xE);     // block-level same swizzle
        const int4 v = hv[pb];
        wreg[4*k]   = (unsigned)v.x; wreg[4*k+1] = (unsigned)v.y;
        wreg[4*k+2] = (unsigned)v.z; wreg[4*k+3] = (unsigned)v.w;
        ps += (unsigned)v.x + (unsigned)v.y + (unsigned)v.z + (unsigned)v.w;
    }
    (void)wreg;
    const unsigned tot  = (ps & 0xFFFFu) + (ps >> 16);
    const unsigned incl = scan64_add(tot);
    const unsigned excl = incl - tot;

    // ---- owner lane per rank: first lane with incl >= T, T = 513-K ----
    const unsigned long long Ba = __ballot(incl >= 257u);
    const unsigned long long Bb = __ballot(incl >= 172u);
    const unsigned long long Bc = __ballot(incl >= 129u);
    const unsigned long long Bd = __ballot(incl >= 104u);
    const int l0 = __ffsll(Ba) - 1, l1 = __ffsll(Bb) - 1,
              l2 = __ffsll(Bc) - 1, l3 = __ffsll(Bd) - 1;

    // owner prefix per rank via readlane at SGPR lane index (no bpermute)
    const unsigned e0 = (unsigned)__builtin_amdgcn_readlane((int)excl, l0);
    const unsigned e1 = (unsigned)__builtin_amdgcn_readlane((int)excl, l1);
    const unsigned e2 = (unsigned)__builtin_amdgcn_readlane((int)excl, l2);
    const unsigned e3 = (unsigned)__builtin_amdgcn_readlane((int)excl, l3);

    // ---- crossing scan: 16-lane groups; owner has 8 words (lanes 8-15 pad) ----
    const int r = lane >> 4;
    const int lsel = (r == 0) ? l0 : (r == 1) ? l1 : (r == 2) ? l2 : l3;
    const int Tr   = (r == 0) ? 257 : (r == 1) ? 172 : (r == 2) ? 129 : 104;
    const unsigned exl = (r == 0) ? e0 : (r == 1) ? e1 : (r == 2) ? e2 : e3;

    const int jw = ((lsel << 3) + (lane & 15)) & 511;  // pad lanes read junk (masked)
    const int pw = jw ^ ((jw >> 3) & 0x38);
    const unsigned w0 = h[pw];
    const unsigned q  = w0 + (w0 << 16);       // packed (even, even+odd)
    const unsigned wt = q >> 16;
    const unsigned sc = scan16_add(wt);
    const unsigned ebase = exl + (sc - wt);    // global prefix before word
    const int      phi   = (int)(ebase + wt);  // global incl prefix at word
    const unsigned long long CB = __ballot(phi >= Tr);

    const float NINF = -__builtin_inff();
    int b_[4], R_[4], al_[4]; float tthr[4];
    {
        const int Ls[4] = {l0, l1, l2, l3};
        const int Ts[4] = {257, 172, 129, 104};
        const int Ks[4] = {256, 341, 384, 409};
        #pragma unroll
        for (int rr = 0; rr < 4; ++rr) {
            const unsigned cb = (unsigned)(CB >> (rr << 4)) & 0xFFFFu;
            const int js = __ffs(cb) - 1;      // true crossing word, 0..7
            const int li = (rr << 4) + js;
            const unsigned qw  = (unsigned)__builtin_amdgcn_readlane((int)q, li);
            const unsigned ebw = (unsigned)__builtin_amdgcn_readlane((int)ebase, li);
            const int  plo  = (int)(ebw + (qw & 0xFFFFu));   // pref at even bin
            const int  phw  = (int)(ebw + (qw >> 16));       // pref at odd bin
            const bool ev   = (plo >= Ts[rr]);
            const int  bsel = (((Ls[rr] << 3) + js) << 1) + (ev ? 0 : 1);
            const int  locp = ev ? plo : phw;
            const int  prvp = ev ? (int)ebw : plo;
            b_[rr]  = bsel;
            R_[rr]  = Ks[rr] - 512 + locp;                   // rank in bin >= 1
            al_[rr] = (prvp == Ts[rr] - 1) ? 1 : 0;          // whole bin admitted
            // exact lower edge of bin bsel (multiple of 2^-8, exact fp32)
            const float t = __uint_as_float((unsigned)(bsel + 0x41000) << 12) - 11.5f;
            tthr[rr] = (bsel < 1) ? NINF : t;                // clamp bin 0: all in
        }
    }

    // ---- exact tail only for partially-admitted bins -> float threshold ----
    int needv[4] = {0,0,0,0}, cntv[4] = {0,0,0,0};
    bool anytb = false;
    #pragma unroll
    for (int rr = 0; rr < 4; ++rr) {
        if (!al_[rr]) {                        // wave-uniform (SGPR) branch
            float cm[8];
            #pragma unroll
            for (int s = 0; s < 8; ++s)
                cm[s] = (bin[s] == b_[rr]) ? x[s] : NINF;
            int R = R_[rr];
            float t; int c;
            while (true) {
                float mk = cm[0];
                #pragma unroll
                for (int s = 1; s < 8; ++s) mk = fmaxf(mk, cm[s]);
                t = wave_fmax_red(mk);
                c = 0;
                #pragma unroll
                for (int s = 0; s < 8; ++s)
                    c += (int)__popcll(__ballot(cm[s] == t));
                if (c >= R) break;
                R -= c;
                #pragma unroll
                for (int s = 0; s < 8; ++s)
                    cm[s] = (cm[s] == t) ? NINF : cm[s];
            }
            tthr[rr] = t; needv[rr] = R; cntv[rr] = c;
            anytb = anytb || (c != R);         // index tiebreak needed?
        }
    }

    float eo[8];
    #pragma unroll
    for (int s = 0; s < 8; ++s) eo[s] = __expf(x[s]);

    float res[8];
    if (!anytb) {
        // ---- fast path: 4 nested float thresholds t1>=t2>=t3>=t4 ----
        const float t1 = tthr[0], t2 = tthr[1], t3 = tthr[2], t4 = tthr[3];
        float z0 = 0.f, z1 = 0.f, z2 = 0.f, z3 = 0.f;
        #pragma unroll
        for (int s = 0; s < 8; ++s) {
            z0 += (x[s] >= t1) ? eo[s] : 0.f;
            z1 += (x[s] >= t2) ? eo[s] : 0.f;
            z2 += (x[s] >= t3) ? eo[s] : 0.f;
            z3 += (x[s] >= t4) ? eo[s] : 0.f;
        }
        const float Z0 = wave_fadd_red(z0);
        const float Z1 = wave_fadd_red(z1);
        const float Z2 = wave_fadd_red(z2);
        const float Z3 = wave_fadd_red(z3);
        const float wz0 = w1p[0] * __builtin_amdgcn_rcpf(Z0);
        const float wz1 = w2p[0] * __builtin_amdgcn_rcpf(Z1);
        const float wz2 = w3p[0] * __builtin_amdgcn_rcpf(Z2);
        const float wz3 = w4p[0] * __builtin_amdgcn_rcpf(Z3);
        const float u4 = wz3, u3 = u4 + wz2, u2 = u3 + wz1, u1 = u2 + wz0;
        #pragma unroll
        for (int s = 0; s < 8; ++s) {
            float c = (x[s] >= t1) ? u1 : u2;
            c = (x[s] >= t2) ? c : u3;
            c = (x[s] >= t3) ? c : u4;
            c = (x[s] >= t4) ? c : 0.f;
            res[s] = eo[s] * c;
        }
    } else {
        // ---- slow path (exact-duplicate tiebreak): general fl bitmask ----
        int fl[8] = {0, 0, 0, 0, 0, 0, 0, 0};
        #pragma unroll
        for (int rr = 0; rr < 4; ++rr) {
            const float t = tthr[rr];
            if (al_[rr] || needv[rr] == cntv[rr]) {
                #pragma unroll
                for (int s = 0; s < 8; ++s)
                    fl[s] |= ((int)(x[s] >= t)) << rr;
            } else {                            // admit lowest original idx
                const unsigned long long ltm = (1ull << lane) - 1ull;
                int basec = 0;
                #pragma unroll
                for (int s = 0; s < 8; ++s)
                    basec += (int)__popcll(__ballot(x[s] == t) & ltm);
                int own = 0;
                #pragma unroll
                for (int s = 0; s < 8; ++s) {
                    const bool eq = (x[s] == t);
                    if (x[s] > t || (eq && (basec + own) < needv[rr]))
                        fl[s] |= (1 << rr);
                    own += eq ? 1 : 0;
                }
            }
        }
        float z0 = 0.f, z1 = 0.f, z2 = 0.f, z3 = 0.f;
        #pragma unroll
        for (int s = 0; s < 8; ++s) {
            z0 += (fl[s] & 1) ? eo[s] : 0.f;
            z1 += (fl[s] & 2) ? eo[s] : 0.f;
            z2 += (fl[s] & 4) ? eo[s] : 0.f;
            z3 += (fl[s] & 8) ? eo[s] : 0.f;
        }
        const float Z0 = wave_fadd_red(z0);
        const float Z1 = wave_fadd_red(z1);
        const float Z2 = wave_fadd_red(z2);
        const float Z3 = wave_fadd_red(z3);
        const float wz0 = w1p[0] * __builtin_amdgcn_rcpf(Z0);
        const float wz1 = w2p[0] * __builtin_amdgcn_rcpf(Z1);
        const float wz2 = w3p[0] * __builtin_amdgcn_rcpf(Z2);
        const float wz3 = w4p[0] * __builtin_amdgcn_rcpf(Z3);
        #pragma unroll
        for (int s = 0; s < 8; ++s) {
            float c = 0.f;
            c += (fl[s] & 1) ? wz0 : 0.f;
            c += (fl[s] & 2) ? wz1 : 0.f;
            c += (fl[s] & 4) ? wz2 : 0.f;
            c += (fl[s] & 8) ? wz3 : 0.f;
            res[s] = eo[s] * c;
        }
    }

    *reinterpret_cast<float4*>(out + base)     = make_float4(res[0], res[1], res[2], res[3]);
    *reinterpret_cast<float4*>(out + base + 4) = make_float4(res[4], res[5], res[6], res[7]);
}

extern "C" void kernel_launch(void* const* d_in, const int* in_sizes, int n_in,
                              void* d_out, int out_size, void* d_ws, size_t ws_size,
                              hipStream_t stream) {
    const float* attn = (const float*)d_in[0];
    const float* w1   = (const float*)d_in[1];
    const float* w2   = (const float*)d_in[2];
    const float* w3   = (const float*)d_in[3];
    const float* w4   = (const float*)d_in[4];
    float* out = (float*)d_out;

    int rows = in_sizes[0] / ROW_C;      // 8*8*512 = 32768
    int blocks = (rows + 3) / 4;         // 4 waves (rows) per 256-thread block
    topk_ms_kernel<<<blocks, 256, 0, stream>>>(attn, w1, w2, w3, w4, out);
}

// Round 7
// 123.158 us; speedup vs baseline: 1.0884x; 1.0179x over previous
//
#include <hip/hip_runtime.h>
#include <math.h>

#define ROW_C 512
#define NBIN 2048
#define NPACK (NBIN / 2)   // two 16-bit counters per int -> 1024 ints = 4KB/wave

// One wave per row, 8 elements/lane (round-3 structure + finer bins).
// Selection of the K-th largest for K in {256,341,384,409}:
//  1. value-uniform 2048-bin histogram, bin width 1/512 (range clamp
//     [-3.5, 0.498046875], +11.5 -> y in [8, 12); bin = bits[22:11] of y,
//     monotone). Fine bins make the threshold bin almost always a singleton
//     -> all-in fast path; clamp bins exact via tail/-inf. Packed u16x2 LDS
//     counters, XOR-swizzled (word j -> j ^ ((j>>3)&0x1C), the R3-verified
//     layout) so int4 reads/writes are bank-conflict-free.
//  2. per-lane packed totals (4 int4) + DPP 64-lane inclusive scan (0 DS);
//     ballots -> owner lanes (SGPR). Crossing scan: 16 lanes per rank, one
//     word per lane (owner has exactly 16 words), 4-step DPP row scan +
//     ballot. NO ds_bpermute: owner prefix and crossing word fetched via
//     v_readlane at SGPR lane indices; per-rank finalize math (bsel, R,
//     all-in, threshold) is wave-uniform.
//  3. nested-set float thresholds t1>=t2>=t3>=t4 (all-in -> exact bin lower
//     edge as_float((bsel+0x82000)<<11) - 11.5, bin 0 -> -inf; partial ->
//     exact tail wave-max via DPP+readlane); membership = x>=t_r; epilogue =
//     4-deep cndmask chain into wz prefix sums.
//  4. rare exact-duplicate index-tiebreak -> wave-uniform fallback (matches
//     jax.lax.top_k lowest-index rule).
// No cross-row ILP (rounds 4/5: neutral-to-negative). No __syncthreads
// (wave-private LDS, in-order DS pipe). Assumes finite inputs.

static __device__ __forceinline__ unsigned scan64_add(unsigned v) {
    int x = (int)v;
    x += __builtin_amdgcn_update_dpp(0, x, 0x111, 0xF, 0xF, false); // row_shr:1
    x += __builtin_amdgcn_update_dpp(0, x, 0x112, 0xF, 0xF, false); // row_shr:2
    x += __builtin_amdgcn_update_dpp(0, x, 0x114, 0xF, 0xE, false); // row_shr:4
    x += __builtin_amdgcn_update_dpp(0, x, 0x118, 0xF, 0xC, false); // row_shr:8
    x += __builtin_amdgcn_update_dpp(0, x, 0x142, 0xA, 0xF, false); // row_bcast:15
    x += __builtin_amdgcn_update_dpp(0, x, 0x143, 0xC, 0xF, false); // row_bcast:31
    return (unsigned)x;
}

static __device__ __forceinline__ unsigned scan16_add(unsigned v) {
    int x = (int)v;
    x += __builtin_amdgcn_update_dpp(0, x, 0x111, 0xF, 0xF, false);
    x += __builtin_amdgcn_update_dpp(0, x, 0x112, 0xF, 0xF, false);
    x += __builtin_amdgcn_update_dpp(0, x, 0x114, 0xF, 0xE, false);
    x += __builtin_amdgcn_update_dpp(0, x, 0x118, 0xF, 0xC, false);
    return (unsigned)x;
}

static __device__ __forceinline__ float wave_fadd_red(float v) {
    float t;
    t = __int_as_float(__builtin_amdgcn_update_dpp(0, __float_as_int(v), 0x111, 0xF, 0xF, false)); v += t;
    t = __int_as_float(__builtin_amdgcn_update_dpp(0, __float_as_int(v), 0x112, 0xF, 0xF, false)); v += t;
    t = __int_as_float(__builtin_amdgcn_update_dpp(0, __float_as_int(v), 0x114, 0xF, 0xE, false)); v += t;
    t = __int_as_float(__builtin_amdgcn_update_dpp(0, __float_as_int(v), 0x118, 0xF, 0xC, false)); v += t;
    t = __int_as_float(__builtin_amdgcn_update_dpp(0, __float_as_int(v), 0x142, 0xA, 0xF, false)); v += t;
    t = __int_as_float(__builtin_amdgcn_update_dpp(0, __float_as_int(v), 0x143, 0xC, 0xF, false)); v += t;
    return __int_as_float(__builtin_amdgcn_readlane(__float_as_int(v), 63));
}

static __device__ __forceinline__ float wave_fmax_red(float v) {
    const int NI = (int)0xFF800000;
    float t;
    t = __int_as_float(__builtin_amdgcn_update_dpp(NI, __float_as_int(v), 0x111, 0xF, 0xF, false)); v = fmaxf(v, t);
    t = __int_as_float(__builtin_amdgcn_update_dpp(NI, __float_as_int(v), 0x112, 0xF, 0xF, false)); v = fmaxf(v, t);
    t = __int_as_float(__builtin_amdgcn_update_dpp(NI, __float_as_int(v), 0x114, 0xF, 0xE, false)); v = fmaxf(v, t);
    t = __int_as_float(__builtin_amdgcn_update_dpp(NI, __float_as_int(v), 0x118, 0xF, 0xC, false)); v = fmaxf(v, t);
    t = __int_as_float(__builtin_amdgcn_update_dpp(NI, __float_as_int(v), 0x142, 0xA, 0xF, false)); v = fmaxf(v, t);
    t = __int_as_float(__builtin_amdgcn_update_dpp(NI, __float_as_int(v), 0x143, 0xC, 0xF, false)); v = fmaxf(v, t);
    return __int_as_float(__builtin_amdgcn_readlane(__float_as_int(v), 63));
}

__global__ __launch_bounds__(256) void topk_ms_kernel(
    const float* __restrict__ attn,
    const float* __restrict__ w1p, const float* __restrict__ w2p,
    const float* __restrict__ w3p, const float* __restrict__ w4p,
    float* __restrict__ out)
{
    __shared__ __align__(16) unsigned hist_all[4][NPACK];

    const int lane = threadIdx.x & 63;
    const int wv   = threadIdx.x >> 6;
    unsigned* h = hist_all[wv];
    int4* hv = (int4*)h;

    const long long row  = (long long)blockIdx.x * 4 + wv;
    const long long base = row * ROW_C + lane * 8;

    const float4 A = *reinterpret_cast<const float4*>(attn + base);
    const float4 B = *reinterpret_cast<const float4*>(attn + base + 4);
    float x[8] = {A.x, A.y, A.z, A.w, B.x, B.y, B.z, B.w};

    int bin[8];
    #pragma unroll
    for (int s = 0; s < 8; ++s) {
        // clamp [-3.5, 255/512] (both exact), +11.5 -> y in [8.0, 11.998046875]
        const float y = __builtin_amdgcn_fmed3f(x[s], -3.5f, 0.498046875f) + 11.5f;
        bin[s] = (int)((__float_as_uint(y) >> 11) & 0x7FFu);   // 0..2047, width 1/512
    }

    // ---- zero histogram (256 int4) ----
    {
        const int4 z = make_int4(0, 0, 0, 0);
        hv[lane] = z; hv[lane + 64] = z; hv[lane + 128] = z; hv[lane + 192] = z;
    }

    // ---- histogram: packed atomic adds, swizzled (word bits[7:5]->[4:2]) ----
    #pragma unroll
    for (int s = 0; s < 8; ++s) {
        const int j  = bin[s] >> 1;
        const int ph = j ^ ((j >> 3) & 0x1C);
        atomicAdd(&h[ph], (bin[s] & 1) ? 0x10000u : 1u);
    }

    // ---- per-lane raw totals of own 32 bins (words 16l..16l+15, 4 int4) ----
    unsigned ps = 0;
    #pragma unroll
    for (int k = 0; k < 4; ++k) {
        const int b  = 4 * lane + k;
        const int pb = b ^ ((b >> 3) & 7);         // int4-level same swizzle
        const int4 v = hv[pb];
        ps += (unsigned)v.x + (unsigned)v.y + (unsigned)v.z + (unsigned)v.w;
    }
    const unsigned tot  = (ps & 0xFFFFu) + (ps >> 16);
    const unsigned incl = scan64_add(tot);
    const unsigned excl = incl - tot;

    // ---- owner lane per rank: first lane with incl >= T, T = 513-K ----
    const unsigned long long Ba = __ballot(incl >= 257u);
    const unsigned long long Bb = __ballot(incl >= 172u);
    const unsigned long long Bc = __ballot(incl >= 129u);
    const unsigned long long Bd = __ballot(incl >= 104u);
    const int l0 = __ffsll(Ba) - 1, l1 = __ffsll(Bb) - 1,
              l2 = __ffsll(Bc) - 1, l3 = __ffsll(Bd) - 1;

    // owner prefix per rank via readlane at SGPR lane index (no bpermute)
    const unsigned e0 = (unsigned)__builtin_amdgcn_readlane((int)excl, l0);
    const unsigned e1 = (unsigned)__builtin_amdgcn_readlane((int)excl, l1);
    const unsigned e2 = (unsigned)__builtin_amdgcn_readlane((int)excl, l2);
    const unsigned e3 = (unsigned)__builtin_amdgcn_readlane((int)excl, l3);

    // ---- crossing scan: 16 lanes per rank, owner has exactly 16 words ----
    const int r = lane >> 4;
    const int lsel = (r == 0) ? l0 : (r == 1) ? l1 : (r == 2) ? l2 : l3;
    const int Tr   = (r == 0) ? 257 : (r == 1) ? 172 : (r == 2) ? 129 : 104;
    const unsigned exl = (r == 0) ? e0 : (r == 1) ? e1 : (r == 2) ? e2 : e3;

    const int jw = (lsel << 4) + (lane & 15);  // logical word index
    const int pw = jw ^ ((jw >> 3) & 0x1C);    // same swizzle as atomics
    const unsigned w0 = h[pw];
    const unsigned q  = w0 + (w0 << 16);       // packed (even, even+odd)
    const unsigned wt = q >> 16;
    const unsigned sc = scan16_add(wt);
    const unsigned ebase = exl + (sc - wt);    // global prefix before word
    const int      phi   = (int)(ebase + wt);  // global incl prefix at word
    const unsigned long long CB = __ballot(phi >= Tr);

    const float NINF = -__builtin_inff();
    int b_[4], R_[4], al_[4]; float tthr[4];
    {
        const int Ls[4] = {l0, l1, l2, l3};
        const int Ts[4] = {257, 172, 129, 104};
        const int Ks[4] = {256, 341, 384, 409};
        #pragma unroll
        for (int rr = 0; rr < 4; ++rr) {
            const unsigned cb = (unsigned)(CB >> (rr << 4)) & 0xFFFFu;
            const int js = __ffs(cb) - 1;      // crossing word, 0..15 (nonzero cb)
            const int li = (rr << 4) + js;
            const unsigned qw  = (unsigned)__builtin_amdgcn_readlane((int)q, li);
            const unsigned ebw = (unsigned)__builtin_amdgcn_readlane((int)ebase, li);
            const int  plo  = (int)(ebw + (qw & 0xFFFFu));   // pref at even bin
            const int  phw  = (int)(ebw + (qw >> 16));       // pref at odd bin
            const bool ev   = (plo >= Ts[rr]);
            const int  bsel = (((Ls[rr] << 4) + js) << 1) + (ev ? 0 : 1);
            const int  locp = ev ? plo : phw;
            const int  prvp = ev ? (int)ebw : plo;
            b_[rr]  = bsel;
            R_[rr]  = Ks[rr] - 512 + locp;                   // rank in bin >= 1
            al_[rr] = (prvp == Ts[rr] - 1) ? 1 : 0;          // whole bin admitted
            // exact lower edge of bin bsel (multiple of 2^-9, exact fp32)
            const float t = __uint_as_float((unsigned)(bsel + 0x82000) << 11) - 11.5f;
            tthr[rr] = (bsel < 1) ? NINF : t;                // clamp bin 0: all in
        }
    }

    // ---- exact tail only for partially-admitted bins -> float threshold ----
    int needv[4] = {0,0,0,0}, cntv[4] = {0,0,0,0};
    bool anytb = false;
    #pragma unroll
    for (int rr = 0; rr < 4; ++rr) {
        if (!al_[rr]) {                        // wave-uniform (SGPR) branch
            float cm[8];
            #pragma unroll
            for (int s = 0; s < 8; ++s)
                cm[s] = (bin[s] == b_[rr]) ? x[s] : NINF;
            int R = R_[rr];
            float t; int c;
            while (true) {
                float mk = cm[0];
                #pragma unroll
                for (int s = 1; s < 8; ++s) mk = fmaxf(mk, cm[s]);
                t = wave_fmax_red(mk);
                c = 0;
                #pragma unroll
                for (int s = 0; s < 8; ++s)
                    c += (int)__popcll(__ballot(cm[s] == t));
                if (c >= R) break;
                R -= c;
                #pragma unroll
                for (int s = 0; s < 8; ++s)
                    cm[s] = (cm[s] == t) ? NINF : cm[s];
            }
            tthr[rr] = t; needv[rr] = R; cntv[rr] = c;
            anytb = anytb || (c != R);         // index tiebreak needed?
        }
    }

    float eo[8];
    #pragma unroll
    for (int s = 0; s < 8; ++s) eo[s] = __expf(x[s]);

    float res[8];
    if (!anytb) {
        // ---- fast path: 4 nested float thresholds t1>=t2>=t3>=t4 ----
        const float t1 = tthr[0], t2 = tthr[1], t3 = tthr[2], t4 = tthr[3];
        float z0 = 0.f, z1 = 0.f, z2 = 0.f, z3 = 0.f;
        #pragma unroll
        for (int s = 0; s < 8; ++s) {
            z0 += (x[s] >= t1) ? eo[s] : 0.f;
            z1 += (x[s] >= t2) ? eo[s] : 0.f;
            z2 += (x[s] >= t3) ? eo[s] : 0.f;
            z3 += (x[s] >= t4) ? eo[s] : 0.f;
        }
        const float Z0 = wave_fadd_red(z0);
        const float Z1 = wave_fadd_red(z1);
        const float Z2 = wave_fadd_red(z2);
        const float Z3 = wave_fadd_red(z3);
        const float wz0 = w1p[0] * __builtin_amdgcn_rcpf(Z0);
        const float wz1 = w2p[0] * __builtin_amdgcn_rcpf(Z1);
        const float wz2 = w3p[0] * __builtin_amdgcn_rcpf(Z2);
        const float wz3 = w4p[0] * __builtin_amdgcn_rcpf(Z3);
        const float u4 = wz3, u3 = u4 + wz2, u2 = u3 + wz1, u1 = u2 + wz0;
        #pragma unroll
        for (int s = 0; s < 8; ++s) {
            float c = (x[s] >= t1) ? u1 : u2;
            c = (x[s] >= t2) ? c : u3;
            c = (x[s] >= t3) ? c : u4;
            c = (x[s] >= t4) ? c : 0.f;
            res[s] = eo[s] * c;
        }
    } else {
        // ---- slow path (exact-duplicate tiebreak): general fl bitmask ----
        int fl[8] = {0, 0, 0, 0, 0, 0, 0, 0};
        #pragma unroll
        for (int rr = 0; rr < 4; ++rr) {
            const float t = tthr[rr];
            if (al_[rr] || needv[rr] == cntv[rr]) {
                #pragma unroll
                for (int s = 0; s < 8; ++s)
                    fl[s] |= ((int)(x[s] >= t)) << rr;
            } else {                            // admit lowest original idx
                const unsigned long long ltm = (1ull << lane) - 1ull;
                int basec = 0;
                #pragma unroll
                for (int s = 0; s < 8; ++s)
                    basec += (int)__popcll(__ballot(x[s] == t) & ltm);
                int own = 0;
                #pragma unroll
                for (int s = 0; s < 8; ++s) {
                    const bool eq = (x[s] == t);
                    if (x[s] > t || (eq && (basec + own) < needv[rr]))
                        fl[s] |= (1 << rr);
                    own += eq ? 1 : 0;
                }
            }
        }
        float z0 = 0.f, z1 = 0.f, z2 = 0.f, z3 = 0.f;
        #pragma unroll
        for (int s = 0; s < 8; ++s) {
            z0 += (fl[s] & 1) ? eo[s] : 0.f;
            z1 += (fl[s] & 2) ? eo[s] : 0.f;
            z2 += (fl[s] & 4) ? eo[s] : 0.f;
            z3 += (fl[s] & 8) ? eo[s] : 0.f;
        }
        const float Z0 = wave_fadd_red(z0);
        const float Z1 = wave_fadd_red(z1);
        const float Z2 = wave_fadd_red(z2);
        const float Z3 = wave_fadd_red(z3);
        const float wz0 = w1p[0] * __builtin_amdgcn_rcpf(Z0);
        const float wz1 = w2p[0] * __builtin_amdgcn_rcpf(Z1);
        const float wz2 = w3p[0] * __builtin_amdgcn_rcpf(Z2);
        const float wz3 = w4p[0] * __builtin_amdgcn_rcpf(Z3);
        #pragma unroll
        for (int s = 0; s < 8; ++s) {
            float c = 0.f;
            c += (fl[s] & 1) ? wz0 : 0.f;
            c += (fl[s] & 2) ? wz1 : 0.f;
            c += (fl[s] & 4) ? wz2 : 0.f;
            c += (fl[s] & 8) ? wz3 : 0.f;
            res[s] = eo[s] * c;
        }
    }

    *reinterpret_cast<float4*>(out + base)     = make_float4(res[0], res[1], res[2], res[3]);
    *reinterpret_cast<float4*>(out + base + 4) = make_float4(res[4], res[5], res[6], res[7]);
}

extern "C" void kernel_launch(void* const* d_in, const int* in_sizes, int n_in,
                              void* d_out, int out_size, void* d_ws, size_t ws_size,
                              hipStream_t stream) {
    const float* attn = (const float*)d_in[0];
    const float* w1   = (const float*)d_in[1];
    const float* w2   = (const float*)d_in[2];
    const float* w3   = (const float*)d_in[3];
    const float* w4   = (const float*)d_in[4];
    float* out = (float*)d_out;

    int rows = in_sizes[0] / ROW_C;      // 8*8*512 = 32768
    int blocks = (rows + 3) / 4;         // 4 waves (rows) per 256-thread block
    topk_ms_kernel<<<blocks, 256, 0, stream>>>(attn, w1, w2, w3, w4, out);
}